// Round 2
// baseline (314.378 us; speedup 1.0000x reference)
//
#include <hip/hip_runtime.h>
#include <math.h>

#define BATCH 32
#define CH    256
#define HH    56
#define WW    56
#define HW    3136
#define KS    7
#define KK    49
#define NIMG  8192          // BATCH*CH
#define PITCH 64            // padded LDS row pitch (floats)
#define PROWS 62            // 56 + 2*3 pad rows
#define PIMG  (PROWS*PITCH) // 3968 floats per padded image
#define IPB   4             // images per conv block

// ---------------- Kernel 1: 8x8 block-mean pool -> p[B,C,49] ----------------
// 4 images/block, 98 threads/image: thread = (pool-row pr, col-quad cq).
// 8x float4 coalesced loads, pair-reduce via one shuffle. No LDS, no barrier.
__global__ __launch_bounds__(392) void pool_kernel(const float* __restrict__ x,
                                                   float* __restrict__ p) {
    const int t   = threadIdx.x;
    const int im  = t / 98, rem = t % 98;
    const int pr  = rem / 14, cq = rem % 14;
    const int img = blockIdx.x * 4 + im;
    const float4* xr = (const float4*)(x + (size_t)img * HW);   // 14 float4 per row
    float4 s4 = make_float4(0.f, 0.f, 0.f, 0.f);
    #pragma unroll
    for (int r = 0; r < 8; ++r) {
        const float4 v = xr[(pr * 8 + r) * 14 + cq];
        s4.x += v.x; s4.y += v.y; s4.z += v.z; s4.w += v.w;
    }
    float s = (s4.x + s4.y) + (s4.z + s4.w);   // 4 cols x 8 rows
    s += __shfl_down(s, 1, 64);                // + partner quad -> full 8x8 cell
    if ((cq & 1) == 0)
        p[(size_t)img * KK + pr * KS + (cq >> 1)] = s * (1.0f / 64.0f);
}

// ------------- Kernel 2: BN batch stats per channel -> scale/shift ----------
__global__ __launch_bounds__(256) void bnstats_kernel(const float* __restrict__ p,
                                                      const float* __restrict__ gamma,
                                                      const float* __restrict__ beta,
                                                      float* __restrict__ scale,
                                                      float* __restrict__ shift) {
    const int c = blockIdx.x;
    float s = 0.f, s2 = 0.f;
    for (int t = threadIdx.x; t < BATCH * KK; t += 256) {
        const int b = t / KK, i = t - b * KK;
        const float v = p[((size_t)b * CH + c) * KK + i];
        s += v; s2 += v * v;
    }
    #pragma unroll
    for (int o = 32; o >= 1; o >>= 1) {
        s  += __shfl_down(s, o, 64);
        s2 += __shfl_down(s2, o, 64);
    }
    __shared__ float r1[4], r2[4];
    const int w = threadIdx.x >> 6;
    if ((threadIdx.x & 63) == 0) { r1[w] = s; r2[w] = s2; }
    __syncthreads();
    if (threadIdx.x == 0) {
        const float S  = r1[0] + r1[1] + r1[2] + r1[3];
        const float S2 = r2[0] + r2[1] + r2[2] + r2[3];
        const float inv = 1.0f / (float)(BATCH * KK);
        const float mu  = S * inv;
        const float var = S2 * inv - mu * mu;       // biased, matches ref
        const float rstd = rsqrtf(var + 1e-5f);
        const float sc = gamma[c] * rstd;
        scale[c] = sc;
        shift[c] = beta[c] - mu * sc;
    }
}

// --- Kernel 3: BN-apply + Linear(49->7) + LayerNorm(C,7) + sigmoid + Linear(7->49) ---
__global__ __launch_bounds__(256) void mid_kernel(const float* __restrict__ p,
                                                  const float* __restrict__ scale,
                                                  const float* __restrict__ shift,
                                                  const float* __restrict__ w0,
                                                  const float* __restrict__ lng,
                                                  const float* __restrict__ lnb,
                                                  const float* __restrict__ w1,
                                                  float* __restrict__ ker) {
    const int b = blockIdx.x, c = threadIdx.x;
    __shared__ float s_w0[KS * KK], s_w1[KK * KS];
    __shared__ float r1[4], r2[4];
    for (int i = threadIdx.x; i < KS * KK; i += 256) { s_w0[i] = w0[i]; s_w1[i] = w1[i]; }
    __syncthreads();
    float pn[KK];
    const float* pp = p + ((size_t)b * CH + c) * KK;
    const float sc = scale[c], sh = shift[c];
    #pragma unroll
    for (int i = 0; i < KK; ++i) pn[i] = pp[i] * sc + sh;
    float v[KS];
    float ls = 0.f, ls2 = 0.f;
    #pragma unroll
    for (int j = 0; j < KS; ++j) {
        float a = 0.f;
        #pragma unroll
        for (int i = 0; i < KK; ++i) a += pn[i] * s_w0[j * KK + i];   // v = pn @ w0^T
        v[j] = a; ls += a; ls2 += a * a;
    }
    #pragma unroll
    for (int o = 32; o >= 1; o >>= 1) {
        ls  += __shfl_down(ls, o, 64);
        ls2 += __shfl_down(ls2, o, 64);
    }
    const int w = threadIdx.x >> 6;
    if ((threadIdx.x & 63) == 0) { r1[w] = ls; r2[w] = ls2; }
    __syncthreads();
    const float S  = r1[0] + r1[1] + r1[2] + r1[3];
    const float S2 = r2[0] + r2[1] + r2[2] + r2[3];
    const float inv = 1.0f / (float)(CH * KS);
    const float m   = S * inv;
    const float var = S2 * inv - m * m;             // biased, matches ref
    const float rs  = rsqrtf(var + 1e-5f);
    float sg[KS];
    #pragma unroll
    for (int j = 0; j < KS; ++j) {
        const float vn = (v[j] - m) * rs * lng[c * KS + j] + lnb[c * KS + j];
        sg[j] = 1.0f / (1.0f + expf(-vn));
    }
    float* ko = ker + ((size_t)b * CH + c) * KK;
    #pragma unroll
    for (int i = 0; i < KK; ++i) {
        float a = 0.f;
        #pragma unroll
        for (int j = 0; j < KS; ++j) a += sg[j] * s_w1[i * KS + j];   // @ w1^T
        ko[i] = a;
    }
}

// ------- Kernel 4: depthwise 7x7 'SAME' conv with per-(b,c) kernels --------
// 4 images/block (448 thr). Per image: 14 col-quads x 8 row-strips(7 rows).
// Thread computes 4 cols x 7 rows via 13 rows x 3 ds_read_b128 (XOR-swizzled
// LDS: col ^= (row&7)<<2 on BOTH staging writes and reads; 16B-granule safe).
__global__ __launch_bounds__(448) void conv_kernel(const float* __restrict__ x,
                                                   const float* __restrict__ ker,
                                                   float* __restrict__ out) {
    __shared__ __align__(16) float pad[IPB * PIMG];
    __shared__ float kfl[IPB * KK];
    const int t    = threadIdx.x;
    const int img0 = blockIdx.x * IPB;
    if (t < IPB * KK) kfl[t] = ker[(size_t)img0 * KK + t];
    // stage 4 zero-padded images, swizzled: dest-linear iteration, src col = pcs ^ sw
    #pragma unroll
    for (int imS = 0; imS < IPB; ++imS) {
        const float* xi = x + (size_t)(img0 + imS) * HW;
        float* pd = pad + imS * PIMG;
        for (int i = t; i < PIMG; i += 448) {
            const int prr = i >> 6, pcs = i & 63;
            const int pc  = pcs ^ ((prr & 7) << 2);
            const int r = prr - 3, cc = pc - 3;
            float v = 0.f;
            if ((unsigned)r < 56u && (unsigned)cc < 56u) v = xi[r * WW + cc];
            pd[i] = v;
        }
    }
    __syncthreads();
    const int im  = t / 112, rem = t % 112;
    const int cq  = rem % 14, st = rem / 14;
    const int oc0 = cq * 4, orow0 = st * 7;
    float kv[KK];
    #pragma unroll
    for (int i = 0; i < KK; ++i) kv[i] = kfl[im * KK + i];
    float acc[7][4];
    #pragma unroll
    for (int a = 0; a < 7; ++a)
        #pragma unroll
        for (int d = 0; d < 4; ++d) acc[a][d] = 0.f;
    const float* pd = pad + im * PIMG;
    #pragma unroll
    for (int ri = 0; ri < 13; ++ri) {
        const int prr = orow0 + ri;
        const int sw  = (prr & 7) << 2;
        const float4 A = *(const float4*)&pd[prr * PITCH + ((oc0    ) ^ sw)];
        const float4 B = *(const float4*)&pd[prr * PITCH + ((oc0 + 4) ^ sw)];
        const float4 C = *(const float4*)&pd[prr * PITCH + ((oc0 + 8) ^ sw)];
        const float w[12] = {A.x, A.y, A.z, A.w, B.x, B.y, B.z, B.w, C.x, C.y, C.z, C.w};
        #pragma unroll
        for (int kr = 0; kr < 7; ++kr) {
            const int orow = ri - kr;
            if (orow < 0 || orow > 6) continue;     // folds at compile time
            #pragma unroll
            for (int kw = 0; kw < 7; ++kw) {
                const float kvv = kv[kr * 7 + kw];
                acc[orow][0] += w[kw    ] * kvv;
                acc[orow][1] += w[kw + 1] * kvv;
                acc[orow][2] += w[kw + 2] * kvv;
                acc[orow][3] += w[kw + 3] * kvv;
            }
        }
    }
    float* oi = out + (size_t)(img0 + im) * HW;
    #pragma unroll
    for (int rr = 0; rr < 7; ++rr) {
        const float4 o4 = make_float4(acc[rr][0], acc[rr][1], acc[rr][2], acc[rr][3]);
        *(float4*)&oi[(orow0 + rr) * WW + oc0] = o4;
    }
}

extern "C" void kernel_launch(void* const* d_in, const int* in_sizes, int n_in,
                              void* d_out, int out_size, void* d_ws, size_t ws_size,
                              hipStream_t stream) {
    const float* x   = (const float*)d_in[0];
    const float* bng = (const float*)d_in[1];
    const float* bnb = (const float*)d_in[2];
    const float* w0  = (const float*)d_in[3];
    const float* lng = (const float*)d_in[4];
    const float* lnb = (const float*)d_in[5];
    const float* w1  = (const float*)d_in[6];
    float* out = (float*)d_out;

    float* ws    = (float*)d_ws;
    float* p     = ws;                       // NIMG*KK floats
    float* scale = p + (size_t)NIMG * KK;    // CH
    float* shift = scale + CH;               // CH
    float* kern  = shift + CH;               // NIMG*KK

    hipLaunchKernelGGL(pool_kernel,    dim3(NIMG / 4), dim3(392), 0, stream, x, p);
    hipLaunchKernelGGL(bnstats_kernel, dim3(CH),       dim3(256), 0, stream, p, bng, bnb, scale, shift);
    hipLaunchKernelGGL(mid_kernel,     dim3(BATCH),    dim3(256), 0, stream, p, scale, shift,
                       w0, lng, lnb, w1, kern);
    hipLaunchKernelGGL(conv_kernel,    dim3(NIMG / IPB), dim3(448), 0, stream, x, kern, out);
}

// Round 3
// 249.554 us; speedup vs baseline: 1.2598x; 1.2598x over previous
//
#include <hip/hip_runtime.h>
#include <math.h>

#define BATCH 32
#define CH    256
#define HH    56
#define WW    56
#define HW    3136
#define KS    7
#define KK    49
#define NIMG  8192           // BATCH*CH
#define CPITCH 72            // conv LDS pitch: 72 mod 32 = 8 (bank-spread), mult of 4 (b128 align)
#define CROWS  62            // 56 + 2*3 pad rows
#define CPIMG  (CROWS*CPITCH) // 4464 floats
#define CIPB   2             // images per conv block

// ---- Kernel 1: 8x8 block-mean pool -> p[img][49], + per-image (sum,sumsq) ----
// 2 images/block, 128 thr/img (98 active): thread = (pr row-group, cq col-quad).
// Coalesced float4 loads; adjacent-lane shuffle merges quads into 8x8 cells.
// Waves 0,1 -> image 0; waves 2,3 -> image 1 (clean per-wave stats reduce).
__global__ __launch_bounds__(256) void pool_kernel(const float* __restrict__ x,
                                                   float* __restrict__ p,
                                                   float2* __restrict__ ss) {
    const int t  = threadIdx.x;
    const int im = t >> 7, tl = t & 127;
    const int img = blockIdx.x * 2 + im;
    const bool active = tl < 98;
    float s = 0.f;
    if (active) {
        const int cq = tl % 14, pr = tl / 14;
        const float4* xr = (const float4*)(x + (size_t)img * HW);
        #pragma unroll
        for (int r = 0; r < 8; ++r) {
            const float4 v = xr[(pr * 8 + r) * 14 + cq];
            s += (v.x + v.y) + (v.z + v.w);
        }
    }
    const float cellv = (s + __shfl_xor(s, 1, 64)) * (1.0f / 64.0f);  // 8x8 mean
    float v = 0.f;
    if (active && !(tl & 1)) {
        const int cq = tl % 14, pr = tl / 14;
        p[(size_t)img * KK + pr * KS + (cq >> 1)] = cellv;
        v = cellv;
    }
    float v2 = v * v;
    #pragma unroll
    for (int o = 32; o >= 1; o >>= 1) {
        v  += __shfl_down(v,  o, 64);
        v2 += __shfl_down(v2, o, 64);
    }
    __shared__ float ps1[4], ps2[4];
    if ((t & 63) == 0) { ps1[t >> 6] = v; ps2[t >> 6] = v2; }
    __syncthreads();
    if (t == 0)  ss[img]     = make_float2(ps1[0] + ps1[1], ps2[0] + ps2[1]);
    if (t == 64) ss[img + 1] = make_float2(ps1[2] + ps1[3], ps2[2] + ps2[3]);
}

// --- Kernel 2: BN finalize + apply + Linear(49->7) + LN(C,7) + sigmoid + Linear(7->49) ---
// One block per sample b; thread = channel c. BN channel stats reduced from ss in-regs.
__global__ __launch_bounds__(256) void mid_kernel(const float* __restrict__ p,
                                                  const float2* __restrict__ ss,
                                                  const float* __restrict__ bng,
                                                  const float* __restrict__ bnb,
                                                  const float* __restrict__ w0,
                                                  const float* __restrict__ lng,
                                                  const float* __restrict__ lnb,
                                                  const float* __restrict__ w1,
                                                  float* __restrict__ ker) {
    const int b = blockIdx.x, c = threadIdx.x;
    __shared__ float s_w0[KS * KK], s_w1[KK * KS];
    __shared__ float r1[4], r2[4];
    for (int i = c; i < KS * KK; i += 256) { s_w0[i] = w0[i]; s_w1[i] = w1[i]; }
    // per-channel BN stats from per-image partials (coalesced float2 loads)
    float S = 0.f, S2 = 0.f;
    #pragma unroll 4
    for (int bb = 0; bb < BATCH; ++bb) {
        const float2 t2 = ss[(size_t)bb * CH + c];
        S += t2.x; S2 += t2.y;
    }
    {
        const float inv  = 1.0f / (float)(BATCH * KK);
        const float mu   = S * inv;
        const float var  = S2 * inv - mu * mu;      // biased, matches ref
        const float rstd = rsqrtf(var + 1e-5f);
        S  = bng[c] * rstd;                         // reuse S  as scale
        S2 = bnb[c] - mu * S;                       // reuse S2 as shift
    }
    __syncthreads();
    float pn[KK];
    const float* pp = p + ((size_t)b * CH + c) * KK;
    #pragma unroll
    for (int i = 0; i < KK; ++i) pn[i] = pp[i] * S + S2;
    float v[KS];
    float ls = 0.f, ls2 = 0.f;
    #pragma unroll
    for (int j = 0; j < KS; ++j) {
        float a = 0.f;
        #pragma unroll
        for (int i = 0; i < KK; ++i) a += pn[i] * s_w0[j * KK + i];   // v = pn @ w0^T
        v[j] = a; ls += a; ls2 += a * a;
    }
    #pragma unroll
    for (int o = 32; o >= 1; o >>= 1) {
        ls  += __shfl_down(ls, o, 64);
        ls2 += __shfl_down(ls2, o, 64);
    }
    const int w = threadIdx.x >> 6;
    if ((threadIdx.x & 63) == 0) { r1[w] = ls; r2[w] = ls2; }
    __syncthreads();
    const float Sv  = r1[0] + r1[1] + r1[2] + r1[3];
    const float Sv2 = r2[0] + r2[1] + r2[2] + r2[3];
    const float inv = 1.0f / (float)(CH * KS);
    const float m   = Sv * inv;
    const float var = Sv2 * inv - m * m;            // biased, matches ref
    const float rs  = rsqrtf(var + 1e-5f);
    float sg[KS];
    #pragma unroll
    for (int j = 0; j < KS; ++j) {
        const float vn = (v[j] - m) * rs * lng[c * KS + j] + lnb[c * KS + j];
        sg[j] = 1.0f / (1.0f + expf(-vn));
    }
    float* ko = ker + ((size_t)b * CH + c) * KK;
    #pragma unroll
    for (int i = 0; i < KK; ++i) {
        float a = 0.f;
        #pragma unroll
        for (int j = 0; j < KS; ++j) a += sg[j] * s_w1[i * KS + j];   // @ w1^T
        ko[i] = a;
    }
}

// ------- Kernel 3: depthwise 7x7 'SAME' conv with per-(b,c) kernels --------
// 2 images/block, 256 thr. Per image: 16 col-quads (q>=14 compute-masked) x
// 8 row-strips(7). Thread: 4 cols x 7 rows, window = 13 rows x 3 ds_read_b128
// off ONE base + immediate offsets. PITCH=72 => every b128 wave-read covers all
// 32 banks exactly 2x (minimal 8 cyc, no swizzle). Taps -> SGPR (wave-uniform).
__global__ __launch_bounds__(256) void conv_kernel(const float* __restrict__ x,
                                                   const float* __restrict__ ker,
                                                   float* __restrict__ out) {
    __shared__ __align__(16) float pad[CIPB * CPIMG];   // 35712 B
    __shared__ float kfl[CIPB * KK];
    const int t    = threadIdx.x;
    const int img0 = blockIdx.x * CIPB;
    if (t < CIPB * KK) kfl[t] = ker[(size_t)img0 * KK + t];
    // zero pass (vector LDS writes), then overwrite interior with the image
    float4* pz = (float4*)pad;
    for (int j = t; j < CIPB * CPIMG / 4; j += 256)
        pz[j] = make_float4(0.f, 0.f, 0.f, 0.f);
    __syncthreads();
    for (int jj = t; jj < CIPB * 784; jj += 256) {      // 784 float4 per image
        const int imS = (jj >= 784) ? 1 : 0;
        const int j   = jj - imS * 784;
        const int r   = j / 14, c4 = j - r * 14;
        const float4 v = *(const float4*)(x + (size_t)(img0 + imS) * HW + r * WW + c4 * 4);
        float* d = pad + imS * CPIMG + (r + 3) * CPITCH + c4 * 4 + 3;
        d[0] = v.x; d[1] = v.y; d[2] = v.z; d[3] = v.w;
    }
    __syncthreads();
    const int im = t >> 7, tl = t & 127;
    const int q = tl & 15, st = tl >> 4;
    const int oc0 = q * 4, orow0 = st * 7;
    // taps: wave is image-uniform -> hoist to SGPRs
    float kv[KK];
    #pragma unroll
    for (int i = 0; i < KK; ++i)
        kv[i] = __int_as_float(__builtin_amdgcn_readfirstlane(__float_as_int(kfl[im * KK + i])));
    const float* pb = pad + im * CPIMG + orow0 * CPITCH + oc0;
    float acc[KS][4];
    #pragma unroll
    for (int a = 0; a < KS; ++a)
        #pragma unroll
        for (int d = 0; d < 4; ++d) acc[a][d] = 0.f;
    #pragma unroll
    for (int ri = 0; ri < 13; ++ri) {
        const float4 A  = *(const float4*)(pb + ri * CPITCH);
        const float4 Bv = *(const float4*)(pb + ri * CPITCH + 4);
        const float4 Cv = *(const float4*)(pb + ri * CPITCH + 8);
        const float w[12] = {A.x, A.y, A.z, A.w, Bv.x, Bv.y, Bv.z, Bv.w,
                             Cv.x, Cv.y, Cv.z, Cv.w};
        #pragma unroll
        for (int kr = 0; kr < KS; ++kr) {
            const int orow = ri - kr;
            if (orow < 0 || orow > 6) continue;         // folds at compile time
            #pragma unroll
            for (int kw = 0; kw < KS; ++kw) {
                const float kvv = kv[kr * KS + kw];
                acc[orow][0] += w[kw    ] * kvv;
                acc[orow][1] += w[kw + 1] * kvv;
                acc[orow][2] += w[kw + 2] * kvv;
                acc[orow][3] += w[kw + 3] * kvv;
            }
        }
    }
    if (q < 14) {
        float* oi = out + (size_t)(img0 + im) * HW;
        #pragma unroll
        for (int rr = 0; rr < KS; ++rr)
            *(float4*)&oi[(orow0 + rr) * WW + oc0] =
                make_float4(acc[rr][0], acc[rr][1], acc[rr][2], acc[rr][3]);
    }
}

extern "C" void kernel_launch(void* const* d_in, const int* in_sizes, int n_in,
                              void* d_out, int out_size, void* d_ws, size_t ws_size,
                              hipStream_t stream) {
    const float* x   = (const float*)d_in[0];
    const float* bng = (const float*)d_in[1];
    const float* bnb = (const float*)d_in[2];
    const float* w0  = (const float*)d_in[3];
    const float* lng = (const float*)d_in[4];
    const float* lnb = (const float*)d_in[5];
    const float* w1  = (const float*)d_in[6];
    float* out = (float*)d_out;

    float* ws   = (float*)d_ws;
    float* p    = ws;                        // NIMG*KK floats
    float* kern = p + (size_t)NIMG * KK;     // NIMG*KK floats
    // per-image (sum,sumsq) partials live in d_out scratch; conv overwrites all of out later
    float2* ss  = (float2*)d_out;            // NIMG float2 = 64 KB

    hipLaunchKernelGGL(pool_kernel, dim3(NIMG / 2),    dim3(256), 0, stream, x, p, ss);
    hipLaunchKernelGGL(mid_kernel,  dim3(BATCH),       dim3(256), 0, stream, p, ss,
                       bng, bnb, w0, lng, lnb, w1, kern);
    hipLaunchKernelGGL(conv_kernel, dim3(NIMG / CIPB), dim3(256), 0, stream, x, kern, out);
}